// Round 1
// baseline (1329.913 us; speedup 1.0000x reference)
//
#include <hip/hip_runtime.h>
#include <hip/hip_bf16.h>

constexpr int N_ = 100000;
constexpr int E_ = 1600000;
constexpr int G_ = 1000;
constexpr int F_ = 16;
constexpr int D_ = 128;
constexpr int C_ = 100;
constexpr int K_ = 2;
constexpr int L_ = 3;
constexpr int NSB = (N_ + 255) / 256;   // scan blocks = 391

// ---------------- init ----------------
__global__ void init_ws(int* __restrict__ deg, int* __restrict__ cursor,
                        float* __restrict__ pooled, float* __restrict__ cnts) {
    int i = blockIdx.x * 256 + threadIdx.x;
    if (i < N_) { deg[i] = 1; cursor[i] = 0; }     // self-loop counted
    if (i < G_ * C_) pooled[i] = 0.f;
    if (i < G_) cnts[i] = 0.f;
}

__global__ void count_deg(const int* __restrict__ dst, int* __restrict__ deg) {
    int e = blockIdx.x * 256 + threadIdx.x;
    if (e < E_) atomicAdd(&deg[dst[e]], 1);
}

__global__ void compute_disq(const int* __restrict__ deg, float* __restrict__ dis) {
    int i = blockIdx.x * 256 + threadIdx.x;
    if (i < N_) dis[i] = 1.0f / sqrtf((float)deg[i]);   // deg >= 1 always
}

// ---------------- CSR build (hierarchical scan) ----------------
__global__ void scan_block_sums(const int* __restrict__ deg, int* __restrict__ bsums) {
    __shared__ int sh[256];
    int i = blockIdx.x * 256 + threadIdx.x;
    int v = (i < N_) ? (deg[i] - 1) : 0;   // counts exclude self-loop
    sh[threadIdx.x] = v;
    __syncthreads();
    for (int off = 128; off > 0; off >>= 1) {
        if (threadIdx.x < off) sh[threadIdx.x] += sh[threadIdx.x + off];
        __syncthreads();
    }
    if (threadIdx.x == 0) bsums[blockIdx.x] = sh[0];
}

__global__ void scan_offsets(int* __restrict__ bsums, int nb) {
    __shared__ int a[512], b[512];
    int t = threadIdx.x;
    int v = (t < nb) ? bsums[t] : 0;
    a[t] = v;
    __syncthreads();
    int* src = a; int* dst = b;
    for (int off = 1; off < 512; off <<= 1) {
        int x = src[t] + ((t >= off) ? src[t - off] : 0);
        dst[t] = x;
        __syncthreads();
        int* tmp = src; src = dst; dst = tmp;
    }
    if (t < nb) bsums[t] = src[t] - v;     // exclusive
}

__global__ void scan_write(const int* __restrict__ deg, const int* __restrict__ boffs,
                           int* __restrict__ rowp) {
    __shared__ int a[256], b[256];
    int t = threadIdx.x;
    int i = blockIdx.x * 256 + t;
    int v = (i < N_) ? (deg[i] - 1) : 0;
    a[t] = v;
    __syncthreads();
    int* src = a; int* dst = b;
    for (int off = 1; off < 256; off <<= 1) {
        int x = src[t] + ((t >= off) ? src[t - off] : 0);
        dst[t] = x;
        __syncthreads();
        int* tmp = src; src = dst; dst = tmp;
    }
    if (i < N_) rowp[i] = boffs[blockIdx.x] + src[t] - v;
    if (i == 0) rowp[N_] = E_;
}

__global__ void fill_csr(const int* __restrict__ srcv, const int* __restrict__ dstv,
                         const int* __restrict__ rowp, int* __restrict__ cursor,
                         int* __restrict__ csr) {
    int e = blockIdx.x * 256 + threadIdx.x;
    if (e >= E_) return;
    int d = dstv[e];
    int pos = atomicAdd(&cursor[d], 1);
    csr[rowp[d] + pos] = srcv[e];
}

// ---------------- embedding: h = x @ W_embed^T ----------------
__global__ __launch_bounds__(128) void embed_kernel(
    const float* __restrict__ x, const float* __restrict__ Wemb,
    float* __restrict__ h) {
    __shared__ float xs[64 * 16];
    int t = threadIdx.x;                      // output dim d (0..127)
    float w[16];
#pragma unroll
    for (int f = 0; f < 16; ++f) w[f] = Wemb[t * 16 + f];
    int n0 = blockIdx.x * 64;
    for (int idx = t; idx < 64 * 16; idx += 128) {
        int gi = n0 * 16 + idx;
        xs[idx] = (gi < N_ * 16) ? x[gi] : 0.f;
    }
    __syncthreads();
    int lim = min(64, N_ - n0);
    for (int j = 0; j < lim; ++j) {
        float acc = 0.f;
#pragma unroll
        for (int f = 0; f < 16; ++f) acc += xs[j * 16 + f] * w[f];
        h[(size_t)(n0 + j) * 128 + t] = acc;
    }
}

// ---------------- GEMM: out[n][c] = sum_k A[n][k] * W[c][k] ----------------
// 32 rows x 128 cols per block, 4x4 per thread, W staged in LDS by k-halves.
__global__ __launch_bounds__(256) void gcn_gemm(
    const float* __restrict__ A, const float* __restrict__ W,
    float* __restrict__ out, int ncols) {
    __shared__ float Wsh[128 * 65];      // [c][kk], stride 65 -> conflict-free
    __shared__ float Ash[32][128];
    int t = threadIdx.x;
    int tx = t & 31;
    int ty = t >> 5;                      // 0..7
    int row0 = blockIdx.x * 32;

    for (int idx = t; idx < 32 * 128; idx += 256) {
        int r = idx >> 7, k = idx & 127;
        int gr = row0 + r;
        Ash[r][k] = (gr < N_) ? A[(size_t)gr * 128 + k] : 0.f;
    }

    float acc[4][4] = {};
    for (int kb = 0; kb < 128; kb += 64) {
        __syncthreads();
        for (int idx = t; idx < 128 * 64; idx += 256) {
            int c = idx >> 6, kk = idx & 63;
            Wsh[c * 65 + kk] = (c < ncols) ? W[c * 128 + kb + kk] : 0.f;
        }
        __syncthreads();
#pragma unroll 4
        for (int kk = 0; kk < 64; ++kk) {
            float w0 = Wsh[(tx      ) * 65 + kk];
            float w1 = Wsh[(tx + 32) * 65 + kk];
            float w2 = Wsh[(tx + 64) * 65 + kk];
            float w3 = Wsh[(tx + 96) * 65 + kk];
            float a0 = Ash[ty     ][kb + kk];
            float a1 = Ash[ty + 8 ][kb + kk];
            float a2 = Ash[ty + 16][kb + kk];
            float a3 = Ash[ty + 24][kb + kk];
            acc[0][0] += a0 * w0; acc[0][1] += a0 * w1; acc[0][2] += a0 * w2; acc[0][3] += a0 * w3;
            acc[1][0] += a1 * w0; acc[1][1] += a1 * w1; acc[1][2] += a1 * w2; acc[1][3] += a1 * w3;
            acc[2][0] += a2 * w0; acc[2][1] += a2 * w1; acc[2][2] += a2 * w2; acc[2][3] += a2 * w3;
            acc[3][0] += a3 * w0; acc[3][1] += a3 * w1; acc[3][2] += a3 * w2; acc[3][3] += a3 * w3;
        }
    }
#pragma unroll
    for (int i = 0; i < 4; ++i) {
        int gr = row0 + ty + 8 * i;
        if (gr < N_) {
            size_t base = (size_t)gr * 128;
            out[base + tx     ] = acc[i][0];
            out[base + tx + 32] = acc[i][1];
            out[base + tx + 64] = acc[i][2];
            out[base + tx + 96] = acc[i][3];
        }
    }
}

// ---------------- GCN aggregate: h[i] = relu(di*(di*m[i] + sum ds*m[s])) ----
__global__ __launch_bounds__(128) void aggregate(
    const float* __restrict__ m, float* __restrict__ hout,
    const int* __restrict__ rowp, const int* __restrict__ csr,
    const float* __restrict__ dis) {
    int node = blockIdx.x;
    int t = threadIdx.x;
    float di = dis[node];
    int beg = rowp[node], end = rowp[node + 1];
    float acc = di * m[(size_t)node * 128 + t];      // self-loop term
    for (int e = beg; e < end; ++e) {
        int s = csr[e];
        acc += dis[s] * m[(size_t)s * 128 + t];
    }
    float v = di * acc;
    hout[(size_t)node * 128 + t] = v > 0.f ? v : 0.f;
}

// ---------------- centroid norms ----------------
__global__ void c2_kernel(const float* __restrict__ cent, float* __restrict__ c2) {
    int c = blockIdx.x;
    int t = threadIdx.x;    // 64
    float v0 = cent[c * 128 + t];
    float v1 = cent[c * 128 + 64 + t];
    float p = v0 * v0 + v1 * v1;
    for (int off = 32; off > 0; off >>= 1) p += __shfl_down(p, off);
    if (t == 0) c2[c] = p;
}

// ---------------- distances + mean-pool (atomic) ----------------
__global__ __launch_bounds__(128) void pool_dist(
    const float* __restrict__ h, const float* __restrict__ dots,
    const float* __restrict__ c2, const int* __restrict__ batch,
    float* __restrict__ pooled, float* __restrict__ cnts) {
    int node = blockIdx.x;
    int t = threadIdx.x;
    float hv = h[(size_t)node * 128 + t];
    float p = hv * hv;
    for (int off = 32; off > 0; off >>= 1) p += __shfl_down(p, off);
    __shared__ float sx[2];
    if ((t & 63) == 0) sx[t >> 6] = p;
    __syncthreads();
    float x2 = sx[0] + sx[1];
    int g = batch[node];
    if (t < C_) {
        float d2 = x2 + c2[t] - 2.0f * dots[(size_t)node * 128 + t];
        d2 = fmaxf(d2, 0.f);
        float d = sqrtf(d2 + 1e-12f);
        atomicAdd(&pooled[g * C_ + t], d);
    }
    if (t == 0) atomicAdd(&cnts[g], 1.f);
}

// ---------------- final: out = (pooled/cnt) @ W_out^T + b_out ----------------
__global__ void final_out(const float* __restrict__ pooled, const float* __restrict__ cnts,
                          const float* __restrict__ W_out, const float* __restrict__ b_out,
                          float* __restrict__ out) {
    int i = blockIdx.x * 256 + threadIdx.x;
    if (i >= G_ * K_) return;
    int g = i / K_, k = i % K_;
    float inv = 1.0f / fmaxf(cnts[g], 1.0f);
    float acc = 0.f;
    for (int c = 0; c < C_; ++c) acc += pooled[g * C_ + c] * W_out[k * C_ + c];
    out[i] = acc * inv + b_out[k];
}

extern "C" void kernel_launch(void* const* d_in, const int* in_sizes, int n_in,
                              void* d_out, int out_size, void* d_ws, size_t ws_size,
                              hipStream_t stream) {
    const float* x       = (const float*)d_in[0];
    const int*   eidx    = (const int*)d_in[1];    // [2][E]: src then dst
    const int*   batch   = (const int*)d_in[2];
    const float* W_embed = (const float*)d_in[3];
    const float* W_convs = (const float*)d_in[4];
    const float* cent    = (const float*)d_in[5];
    const float* W_out   = (const float*)d_in[6];
    const float* b_out   = (const float*)d_in[7];
    float* out = (float*)d_out;

    char* p = (char*)d_ws;
    float* h    = (float*)p; p += (size_t)N_ * D_ * 4;
    float* m    = (float*)p; p += (size_t)N_ * D_ * 4;
    int*   deg  = (int*)p;   p += (size_t)N_ * 4;
    float* dis  = (float*)p; p += (size_t)N_ * 4;
    int*   rowp = (int*)p;   p += (size_t)(N_ + 2) * 4;
    int*   curs = (int*)p;   p += (size_t)N_ * 4;
    int*   csr  = (int*)p;   p += (size_t)E_ * 4;
    int*   bsum = (int*)p;   p += (size_t)512 * 4;
    float* c2   = (float*)p; p += (size_t)128 * 4;
    float* pool = (float*)p; p += (size_t)G_ * C_ * 4;
    float* cnts = (float*)p; p += (size_t)G_ * 4;

    const int* esrc = eidx;
    const int* edst = eidx + E_;

    init_ws<<<(N_ + 255) / 256, 256, 0, stream>>>(deg, curs, pool, cnts);
    count_deg<<<(E_ + 255) / 256, 256, 0, stream>>>(edst, deg);
    compute_disq<<<(N_ + 255) / 256, 256, 0, stream>>>(deg, dis);
    scan_block_sums<<<NSB, 256, 0, stream>>>(deg, bsum);
    scan_offsets<<<1, 512, 0, stream>>>(bsum, NSB);
    scan_write<<<NSB, 256, 0, stream>>>(deg, bsum, rowp);
    fill_csr<<<(E_ + 255) / 256, 256, 0, stream>>>(esrc, edst, rowp, curs, csr);

    embed_kernel<<<(N_ + 63) / 64, 128, 0, stream>>>(x, W_embed, h);

    for (int l = 0; l < L_; ++l) {
        gcn_gemm<<<(N_ + 31) / 32, 256, 0, stream>>>(h, W_convs + (size_t)l * D_ * D_, m, 128);
        aggregate<<<N_, 128, 0, stream>>>(m, h, rowp, csr, dis);
    }

    // dots = h @ centroids^T  (cols 100..127 zero-padded)
    gcn_gemm<<<(N_ + 31) / 32, 256, 0, stream>>>(h, cent, m, 100);
    c2_kernel<<<C_, 64, 0, stream>>>(cent, c2);
    pool_dist<<<N_, 128, 0, stream>>>(h, m, c2, batch, pool, cnts);
    final_out<<<(G_ * K_ + 255) / 256, 256, 0, stream>>>(pool, cnts, W_out, b_out, out);
}

// Round 2
// 868.736 us; speedup vs baseline: 1.5309x; 1.5309x over previous
//
#include <hip/hip_runtime.h>
#include <hip/hip_bf16.h>

constexpr int N_ = 100000;
constexpr int E_ = 1600000;
constexpr int G_ = 1000;
constexpr int D_ = 128;
constexpr int C_ = 100;
constexpr int K_ = 2;
constexpr int L_ = 3;
constexpr int NSB = (N_ + 255) / 256;   // scan blocks = 391

// ---------------- init ----------------
__global__ void init_ws(int* __restrict__ deg, int* __restrict__ cursor) {
    int i = blockIdx.x * 256 + threadIdx.x;
    if (i < N_) { deg[i] = 1; cursor[i] = 0; }     // self-loop counted
}

__global__ void count_deg(const int* __restrict__ dst, int* __restrict__ deg) {
    int e = blockIdx.x * 256 + threadIdx.x;
    if (e < E_) atomicAdd(&deg[dst[e]], 1);
}

__global__ void compute_disq(const int* __restrict__ deg, float* __restrict__ dis) {
    int i = blockIdx.x * 256 + threadIdx.x;
    if (i < N_) dis[i] = 1.0f / sqrtf((float)deg[i]);   // deg >= 1 always
}

// ---------------- CSR build (hierarchical scan) ----------------
__global__ void scan_block_sums(const int* __restrict__ deg, int* __restrict__ bsums) {
    __shared__ int sh[256];
    int i = blockIdx.x * 256 + threadIdx.x;
    int v = (i < N_) ? (deg[i] - 1) : 0;   // counts exclude self-loop
    sh[threadIdx.x] = v;
    __syncthreads();
    for (int off = 128; off > 0; off >>= 1) {
        if (threadIdx.x < off) sh[threadIdx.x] += sh[threadIdx.x + off];
        __syncthreads();
    }
    if (threadIdx.x == 0) bsums[blockIdx.x] = sh[0];
}

__global__ void scan_offsets(int* __restrict__ bsums, int nb) {
    __shared__ int a[512], b[512];
    int t = threadIdx.x;
    int v = (t < nb) ? bsums[t] : 0;
    a[t] = v;
    __syncthreads();
    int* src = a; int* dst = b;
    for (int off = 1; off < 512; off <<= 1) {
        int x = src[t] + ((t >= off) ? src[t - off] : 0);
        dst[t] = x;
        __syncthreads();
        int* tmp = src; src = dst; dst = tmp;
    }
    if (t < nb) bsums[t] = src[t] - v;     // exclusive
}

__global__ void scan_write(const int* __restrict__ deg, const int* __restrict__ boffs,
                           int* __restrict__ rowp) {
    __shared__ int a[256], b[256];
    int t = threadIdx.x;
    int i = blockIdx.x * 256 + t;
    int v = (i < N_) ? (deg[i] - 1) : 0;
    a[t] = v;
    __syncthreads();
    int* src = a; int* dst = b;
    for (int off = 1; off < 256; off <<= 1) {
        int x = src[t] + ((t >= off) ? src[t - off] : 0);
        dst[t] = x;
        __syncthreads();
        int* tmp = src; src = dst; dst = tmp;
    }
    if (i < N_) rowp[i] = boffs[blockIdx.x] + src[t] - v;
    if (i == 0) rowp[N_] = E_;
}

__global__ void fill_csr(const int* __restrict__ srcv, const int* __restrict__ dstv,
                         const int* __restrict__ rowp, int* __restrict__ cursor,
                         int* __restrict__ csr) {
    int e = blockIdx.x * 256 + threadIdx.x;
    if (e >= E_) return;
    int d = dstv[e];
    int pos = atomicAdd(&cursor[d], 1);
    csr[rowp[d] + pos] = srcv[e];
}

// ---------------- embedding: h = x @ W_embed^T ----------------
__global__ __launch_bounds__(128) void embed_kernel(
    const float* __restrict__ x, const float* __restrict__ Wemb,
    float* __restrict__ h) {
    __shared__ float xs[64 * 16];
    int t = threadIdx.x;                      // output dim d (0..127)
    float w[16];
#pragma unroll
    for (int f = 0; f < 16; ++f) w[f] = Wemb[t * 16 + f];
    int n0 = blockIdx.x * 64;
    for (int idx = t; idx < 64 * 16; idx += 128) {
        int gi = n0 * 16 + idx;
        xs[idx] = (gi < N_ * 16) ? x[gi] : 0.f;
    }
    __syncthreads();
    int lim = min(64, N_ - n0);
    for (int j = 0; j < lim; ++j) {
        float acc = 0.f;
#pragma unroll
        for (int f = 0; f < 16; ++f) acc += xs[j * 16 + f] * w[f];
        h[(size_t)(n0 + j) * 128 + t] = acc;
    }
}

// ---------------- GEMM: out[n][c] = scale[n] * sum_k A[n][k]*W[c][k] -------
// 32 rows x 128 cols per block; thread owns 4 rows x 4 consecutive cols.
// W transposed-staged so the 4-col read is one ds_read_b128.
__global__ __launch_bounds__(256) void gcn_gemm(
    const float* __restrict__ A, const float* __restrict__ W,
    float* __restrict__ out, int ncols, const float* __restrict__ scale) {
    __shared__ float Ash[32 * 128];
    __shared__ float WshT[64 * 132];     // [kk][c], pad 132 (16B-aligned rows)
    int t = threadIdx.x;
    int tx = t & 31;                     // col group: cols 4tx..4tx+3
    int ty = t >> 5;                     // row group: rows ty+8i
    int row0 = blockIdx.x * 32;          // N_ % 32 == 0 -> no guards

    for (int idx = t; idx < 32 * 32; idx += 256) {
        int r = idx >> 5, c4 = (idx & 31) << 2;
        *(float4*)&Ash[r * 128 + c4] =
            *(const float4*)&A[(size_t)(row0 + r) * 128 + c4];
    }

    float4 acc[4];
    acc[0] = acc[1] = acc[2] = acc[3] = make_float4(0.f, 0.f, 0.f, 0.f);

    for (int kb = 0; kb < 128; kb += 64) {
        __syncthreads();
        for (int idx = t; idx < 128 * 16; idx += 256) {
            int c = idx >> 4, q = (idx & 15) << 2;
            float4 w = make_float4(0.f, 0.f, 0.f, 0.f);
            if (c < ncols) w = *(const float4*)&W[c * 128 + kb + q];
            WshT[(q + 0) * 132 + c] = w.x;
            WshT[(q + 1) * 132 + c] = w.y;
            WshT[(q + 2) * 132 + c] = w.z;
            WshT[(q + 3) * 132 + c] = w.w;
        }
        __syncthreads();
#pragma unroll 4
        for (int kk = 0; kk < 64; ++kk) {
            float4 w = *(float4*)&WshT[kk * 132 + (tx << 2)];
            float a0 = Ash[(ty     ) * 128 + kb + kk];
            float a1 = Ash[(ty +  8) * 128 + kb + kk];
            float a2 = Ash[(ty + 16) * 128 + kb + kk];
            float a3 = Ash[(ty + 24) * 128 + kb + kk];
            acc[0].x += a0 * w.x; acc[0].y += a0 * w.y; acc[0].z += a0 * w.z; acc[0].w += a0 * w.w;
            acc[1].x += a1 * w.x; acc[1].y += a1 * w.y; acc[1].z += a1 * w.z; acc[1].w += a1 * w.w;
            acc[2].x += a2 * w.x; acc[2].y += a2 * w.y; acc[2].z += a2 * w.z; acc[2].w += a2 * w.w;
            acc[3].x += a3 * w.x; acc[3].y += a3 * w.y; acc[3].z += a3 * w.z; acc[3].w += a3 * w.w;
        }
    }
#pragma unroll
    for (int i = 0; i < 4; ++i) {
        int gr = row0 + ty + 8 * i;
        float s = scale ? scale[gr] : 1.0f;
        float4 v = acc[i];
        v.x *= s; v.y *= s; v.z *= s; v.w *= s;
        *(float4*)&out[(size_t)gr * 128 + (tx << 2)] = v;
    }
}

// ---------------- GCN aggregate: h[i] = relu(di * sum_{s in nbr+self} m'[s])
// m' is pre-scaled by dis[src] in the GEMM epilogue.
// 256 threads; each half-wave (32 lanes) owns one node; float4 row gathers
// (one wave instr = 2 rows); csr indices preloaded + shfl-broadcast.
__global__ __launch_bounds__(256) void aggregate(
    const float* __restrict__ m, float* __restrict__ hout,
    const int* __restrict__ rowp, const int* __restrict__ csr,
    const float* __restrict__ dis, float* __restrict__ x2out) {
    int t = threadIdx.x;
    int lane = t & 63;
    int l32 = lane & 31;
    int hbase = lane & 32;                       // 0 | 32
    int node = blockIdx.x * 8 + ((t >> 6) << 1) + (hbase >> 5);   // N_ % 8 == 0
    const float4* m4 = (const float4*)m;

    float4 acc = m4[(size_t)node * 32 + l32];    // self-loop term
    int beg = rowp[node], end = rowp[node + 1];
    for (int base = beg; base < end; base += 32) {
        int cnt = end - base; if (cnt > 32) cnt = 32;
        int myidx = (l32 < cnt) ? csr[base + l32] : 0;
        int j = 0;
        for (; j + 4 <= cnt; j += 4) {
            int s0 = __shfl(myidx, hbase + j);
            int s1 = __shfl(myidx, hbase + j + 1);
            int s2 = __shfl(myidx, hbase + j + 2);
            int s3 = __shfl(myidx, hbase + j + 3);
            float4 v0 = m4[(size_t)s0 * 32 + l32];
            float4 v1 = m4[(size_t)s1 * 32 + l32];
            float4 v2 = m4[(size_t)s2 * 32 + l32];
            float4 v3 = m4[(size_t)s3 * 32 + l32];
            acc.x += (v0.x + v1.x) + (v2.x + v3.x);
            acc.y += (v0.y + v1.y) + (v2.y + v3.y);
            acc.z += (v0.z + v1.z) + (v2.z + v3.z);
            acc.w += (v0.w + v1.w) + (v2.w + v3.w);
        }
        for (; j < cnt; ++j) {
            int s = __shfl(myidx, hbase + j);
            float4 v = m4[(size_t)s * 32 + l32];
            acc.x += v.x; acc.y += v.y; acc.z += v.z; acc.w += v.w;
        }
    }
    float di = dis[node];
    float4 hv;
    hv.x = fmaxf(di * acc.x, 0.f);
    hv.y = fmaxf(di * acc.y, 0.f);
    hv.z = fmaxf(di * acc.z, 0.f);
    hv.w = fmaxf(di * acc.w, 0.f);
    ((float4*)hout)[(size_t)node * 32 + l32] = hv;
    if (x2out) {                                  // row norm, free in registers
        float p = hv.x * hv.x + hv.y * hv.y + hv.z * hv.z + hv.w * hv.w;
        p += __shfl_xor(p, 1);
        p += __shfl_xor(p, 2);
        p += __shfl_xor(p, 4);
        p += __shfl_xor(p, 8);
        p += __shfl_xor(p, 16);
        if (l32 == 0) x2out[node] = p;
    }
}

// ---------------- centroid norms ----------------
__global__ void c2_kernel(const float* __restrict__ cent, float* __restrict__ c2) {
    int c = blockIdx.x;
    int t = threadIdx.x;    // 64
    float v0 = cent[c * 128 + t];
    float v1 = cent[c * 128 + 64 + t];
    float p = v0 * v0 + v1 * v1;
    for (int off = 32; off > 0; off >>= 1) p += __shfl_down(p, off);
    if (t == 0) c2[c] = p;
}

// ---------------- per-graph mean-pool of distances (batch is sorted) -------
__global__ __launch_bounds__(128) void pool_graph(
    const float* __restrict__ dots, const float* __restrict__ x2,
    const float* __restrict__ c2, const int* __restrict__ batch,
    float* __restrict__ pooled) {
    int g = blockIdx.x;
    int t = threadIdx.x;
    int lo = 0, hi = N_;
    while (lo < hi) { int mid = (lo + hi) >> 1; if (batch[mid] < g) lo = mid + 1; else hi = mid; }
    int s = lo;
    hi = N_;
    while (lo < hi) { int mid = (lo + hi) >> 1; if (batch[mid] < g + 1) lo = mid + 1; else hi = mid; }
    int e = lo;
    if (t >= C_) return;
    float cv = c2[t];
    float a0 = 0.f, a1 = 0.f, a2 = 0.f, a3 = 0.f;
    int n = s;
    for (; n + 4 <= e; n += 4) {
        float d0 = dots[(size_t)(n    ) * 128 + t];
        float d1 = dots[(size_t)(n + 1) * 128 + t];
        float d2 = dots[(size_t)(n + 2) * 128 + t];
        float d3 = dots[(size_t)(n + 3) * 128 + t];
        float x0 = x2[n], x1 = x2[n + 1], x2v = x2[n + 2], x3 = x2[n + 3];
        a0 += sqrtf(fmaxf(x0  + cv - 2.f * d0, 0.f) + 1e-12f);
        a1 += sqrtf(fmaxf(x1  + cv - 2.f * d1, 0.f) + 1e-12f);
        a2 += sqrtf(fmaxf(x2v + cv - 2.f * d2, 0.f) + 1e-12f);
        a3 += sqrtf(fmaxf(x3  + cv - 2.f * d3, 0.f) + 1e-12f);
    }
    for (; n < e; ++n) {
        float d = dots[(size_t)n * 128 + t];
        a0 += sqrtf(fmaxf(x2[n] + cv - 2.f * d, 0.f) + 1e-12f);
    }
    float inv = 1.0f / fmaxf((float)(e - s), 1.0f);
    pooled[g * C_ + t] = (a0 + a1 + a2 + a3) * inv;
}

// ---------------- final: out = pooled @ W_out^T + b_out ----------------
__global__ void final_out(const float* __restrict__ pooled,
                          const float* __restrict__ W_out, const float* __restrict__ b_out,
                          float* __restrict__ out) {
    int i = blockIdx.x * 256 + threadIdx.x;
    if (i >= G_ * K_) return;
    int g = i >> 1, k = i & 1;
    float acc = 0.f;
    for (int c = 0; c < C_; ++c) acc += pooled[g * C_ + c] * W_out[k * C_ + c];
    out[i] = acc + b_out[k];
}

extern "C" void kernel_launch(void* const* d_in, const int* in_sizes, int n_in,
                              void* d_out, int out_size, void* d_ws, size_t ws_size,
                              hipStream_t stream) {
    const float* x       = (const float*)d_in[0];
    const int*   eidx    = (const int*)d_in[1];    // [2][E]: src then dst
    const int*   batch   = (const int*)d_in[2];
    const float* W_embed = (const float*)d_in[3];
    const float* W_convs = (const float*)d_in[4];
    const float* cent    = (const float*)d_in[5];
    const float* W_out   = (const float*)d_in[6];
    const float* b_out   = (const float*)d_in[7];
    float* out = (float*)d_out;

    char* p = (char*)d_ws;
    float* h    = (float*)p; p += (size_t)N_ * D_ * 4;
    float* m    = (float*)p; p += (size_t)N_ * D_ * 4;
    int*   deg  = (int*)p;   p += (size_t)N_ * 4;
    float* dis  = (float*)p; p += (size_t)N_ * 4;
    int*   rowp = (int*)p;   p += (size_t)(N_ + 2) * 4;
    int*   curs = (int*)p;   p += (size_t)N_ * 4;
    int*   csr  = (int*)p;   p += (size_t)E_ * 4;
    int*   bsum = (int*)p;   p += (size_t)512 * 4;
    float* c2   = (float*)p; p += (size_t)128 * 4;
    float* x2   = (float*)p; p += (size_t)N_ * 4;
    float* pool = (float*)p; p += (size_t)G_ * C_ * 4;

    const int* esrc = eidx;
    const int* edst = eidx + E_;

    init_ws<<<(N_ + 255) / 256, 256, 0, stream>>>(deg, curs);
    count_deg<<<(E_ + 255) / 256, 256, 0, stream>>>(edst, deg);
    compute_disq<<<(N_ + 255) / 256, 256, 0, stream>>>(deg, dis);
    scan_block_sums<<<NSB, 256, 0, stream>>>(deg, bsum);
    scan_offsets<<<1, 512, 0, stream>>>(bsum, NSB);
    scan_write<<<NSB, 256, 0, stream>>>(deg, bsum, rowp);
    fill_csr<<<(E_ + 255) / 256, 256, 0, stream>>>(esrc, edst, rowp, curs, csr);

    embed_kernel<<<(N_ + 63) / 64, 128, 0, stream>>>(x, W_embed, h);

    for (int l = 0; l < L_; ++l) {
        gcn_gemm<<<N_ / 32, 256, 0, stream>>>(h, W_convs + (size_t)l * D_ * D_, m, 128, dis);
        aggregate<<<N_ / 8, 256, 0, stream>>>(m, h, rowp, csr, dis,
                                              (l == L_ - 1) ? x2 : nullptr);
    }

    // dots = h @ centroids^T  (cols 100..127 zero-padded)
    gcn_gemm<<<N_ / 32, 256, 0, stream>>>(h, cent, m, 100, nullptr);
    c2_kernel<<<C_, 64, 0, stream>>>(cent, c2);
    pool_graph<<<G_, 128, 0, stream>>>(m, x2, c2, batch, pool);
    final_out<<<(G_ * K_ + 255) / 256, 256, 0, stream>>>(pool, W_out, b_out, out);
}

// Round 3
// 801.831 us; speedup vs baseline: 1.6586x; 1.0834x over previous
//
#include <hip/hip_runtime.h>
#include <hip/hip_bf16.h>

constexpr int N_ = 100000;
constexpr int E_ = 1600000;
constexpr int G_ = 1000;
constexpr int D_ = 128;
constexpr int C_ = 100;
constexpr int K_ = 2;
constexpr int L_ = 3;
constexpr int NSB = (N_ + 255) / 256;   // scan blocks = 391

// ---------------- init ----------------
__global__ void init_ws(int* __restrict__ deg, int* __restrict__ cursor) {
    int i = blockIdx.x * 256 + threadIdx.x;
    if (i < N_) { deg[i] = 1; cursor[i] = 0; }     // self-loop counted
}

__global__ void count_deg(const int* __restrict__ dst, int* __restrict__ deg) {
    int e = blockIdx.x * 256 + threadIdx.x;
    if (e < E_) atomicAdd(&deg[dst[e]], 1);
}

__global__ void compute_disq(const int* __restrict__ deg, float* __restrict__ dis) {
    int i = blockIdx.x * 256 + threadIdx.x;
    if (i < N_) dis[i] = 1.0f / sqrtf((float)deg[i]);   // deg >= 1 always
}

// ---------------- CSR build (hierarchical scan) ----------------
__global__ void scan_block_sums(const int* __restrict__ deg, int* __restrict__ bsums) {
    __shared__ int sh[256];
    int i = blockIdx.x * 256 + threadIdx.x;
    int v = (i < N_) ? (deg[i] - 1) : 0;   // counts exclude self-loop
    sh[threadIdx.x] = v;
    __syncthreads();
    for (int off = 128; off > 0; off >>= 1) {
        if (threadIdx.x < off) sh[threadIdx.x] += sh[threadIdx.x + off];
        __syncthreads();
    }
    if (threadIdx.x == 0) bsums[blockIdx.x] = sh[0];
}

__global__ void scan_offsets(int* __restrict__ bsums, int nb) {
    __shared__ int a[512], b[512];
    int t = threadIdx.x;
    int v = (t < nb) ? bsums[t] : 0;
    a[t] = v;
    __syncthreads();
    int* src = a; int* dst = b;
    for (int off = 1; off < 512; off <<= 1) {
        int x = src[t] + ((t >= off) ? src[t - off] : 0);
        dst[t] = x;
        __syncthreads();
        int* tmp = src; src = dst; dst = tmp;
    }
    if (t < nb) bsums[t] = src[t] - v;     // exclusive
}

__global__ void scan_write(const int* __restrict__ deg, const int* __restrict__ boffs,
                           int* __restrict__ rowp) {
    __shared__ int a[256], b[256];
    int t = threadIdx.x;
    int i = blockIdx.x * 256 + t;
    int v = (i < N_) ? (deg[i] - 1) : 0;
    a[t] = v;
    __syncthreads();
    int* src = a; int* dst = b;
    for (int off = 1; off < 256; off <<= 1) {
        int x = src[t] + ((t >= off) ? src[t - off] : 0);
        dst[t] = x;
        __syncthreads();
        int* tmp = src; src = dst; dst = tmp;
    }
    if (i < N_) rowp[i] = boffs[blockIdx.x] + src[t] - v;
    if (i == 0) rowp[N_] = E_;
}

__global__ void fill_csr(const int* __restrict__ srcv, const int* __restrict__ dstv,
                         const int* __restrict__ rowp, int* __restrict__ cursor,
                         int* __restrict__ csr) {
    int e = blockIdx.x * 256 + threadIdx.x;
    if (e >= E_) return;
    int d = dstv[e];
    int pos = atomicAdd(&cursor[d], 1);
    csr[rowp[d] + pos] = srcv[e];
}

// ---------------- embedding: h = x @ W_embed^T ----------------
__global__ __launch_bounds__(128) void embed_kernel(
    const float* __restrict__ x, const float* __restrict__ Wemb,
    float* __restrict__ h) {
    __shared__ float4 xs[64 * 4];
    int t = threadIdx.x;                      // output dim d (0..127)
    float w[16];
#pragma unroll
    for (int f = 0; f < 16; ++f) w[f] = Wemb[t * 16 + f];
    int n0 = blockIdx.x * 64;
    const float4* x4 = (const float4*)x;
    for (int idx = t; idx < 64 * 4; idx += 128) {
        int gi = n0 * 4 + idx;
        xs[idx] = (gi < N_ * 4) ? x4[gi] : make_float4(0.f, 0.f, 0.f, 0.f);
    }
    __syncthreads();
    int lim = min(64, N_ - n0);
    for (int j = 0; j < lim; ++j) {
        float4 x0 = xs[j * 4 + 0], x1 = xs[j * 4 + 1];
        float4 x2 = xs[j * 4 + 2], x3 = xs[j * 4 + 3];
        float acc = x0.x * w[0] + x0.y * w[1] + x0.z * w[2] + x0.w * w[3]
                  + x1.x * w[4] + x1.y * w[5] + x1.z * w[6] + x1.w * w[7]
                  + x2.x * w[8] + x2.y * w[9] + x2.z * w[10] + x2.w * w[11]
                  + x3.x * w[12] + x3.y * w[13] + x3.z * w[14] + x3.w * w[15];
        h[(size_t)(n0 + j) * 128 + t] = acc;
    }
}

// ---------------- GEMM: out[n][c] = scale[n] * sum_k A[n][k]*W[c][k] -------
// 64 rows x 128 cols per block; thread owns 8 rows x 4 consecutive cols.
// WshT[k][c] stride-128: transpose-staged with lane-per-column mapping
// (conflict-free b32 writes), inner read = one ds_read_b128 per kk.
__global__ __launch_bounds__(256) void gcn_gemm(
    const float* __restrict__ A, const float* __restrict__ W,
    float* __restrict__ out, int ncols, const float* __restrict__ scale) {
    __shared__ float Ash[64][64];       // [r][kloc]
    __shared__ float WshT[64][128];     // [kloc][c]
    int t = threadIdx.x;
    int tx = t & 31;                    // col quad: cols 4tx..4tx+3
    int ty = t >> 5;                    // 0..7: rows ty + 8i
    int row0 = blockIdx.x * 64;

    float4 acc[8];
#pragma unroll
    for (int i = 0; i < 8; ++i) acc[i] = make_float4(0.f, 0.f, 0.f, 0.f);

    for (int kb = 0; kb < 128; kb += 64) {
        __syncthreads();
        // stage A rows (coalesced float4 reads, balanced LDS writes)
        for (int idx = t; idx < 64 * 16; idx += 256) {
            int r = idx >> 4, kq = (idx & 15) << 2;
            int gr = row0 + r;
            float4 v = (gr < N_) ? *(const float4*)&A[(size_t)gr * 128 + kb + kq]
                                 : make_float4(0.f, 0.f, 0.f, 0.f);
            *(float4*)&Ash[r][kq] = v;
        }
        // stage W transposed: lane-per-column -> conflict-free b32 writes
        for (int idx = t; idx < 128 * 16; idx += 256) {
            int c = idx & 127, q = (idx >> 7) << 2;   // q = 0,4,..,60
            float4 w = (c < ncols) ? *(const float4*)&W[c * 128 + kb + q]
                                   : make_float4(0.f, 0.f, 0.f, 0.f);
            WshT[q + 0][c] = w.x;
            WshT[q + 1][c] = w.y;
            WshT[q + 2][c] = w.z;
            WshT[q + 3][c] = w.w;
        }
        __syncthreads();
#pragma unroll 4
        for (int kk = 0; kk < 64; ++kk) {
            float4 w = *(float4*)&WshT[kk][tx << 2];
            float a0 = Ash[ty     ][kk];
            float a1 = Ash[ty +  8][kk];
            float a2 = Ash[ty + 16][kk];
            float a3 = Ash[ty + 24][kk];
            float a4 = Ash[ty + 32][kk];
            float a5 = Ash[ty + 40][kk];
            float a6 = Ash[ty + 48][kk];
            float a7 = Ash[ty + 56][kk];
            acc[0].x += a0 * w.x; acc[0].y += a0 * w.y; acc[0].z += a0 * w.z; acc[0].w += a0 * w.w;
            acc[1].x += a1 * w.x; acc[1].y += a1 * w.y; acc[1].z += a1 * w.z; acc[1].w += a1 * w.w;
            acc[2].x += a2 * w.x; acc[2].y += a2 * w.y; acc[2].z += a2 * w.z; acc[2].w += a2 * w.w;
            acc[3].x += a3 * w.x; acc[3].y += a3 * w.y; acc[3].z += a3 * w.z; acc[3].w += a3 * w.w;
            acc[4].x += a4 * w.x; acc[4].y += a4 * w.y; acc[4].z += a4 * w.z; acc[4].w += a4 * w.w;
            acc[5].x += a5 * w.x; acc[5].y += a5 * w.y; acc[5].z += a5 * w.z; acc[5].w += a5 * w.w;
            acc[6].x += a6 * w.x; acc[6].y += a6 * w.y; acc[6].z += a6 * w.z; acc[6].w += a6 * w.w;
            acc[7].x += a7 * w.x; acc[7].y += a7 * w.y; acc[7].z += a7 * w.z; acc[7].w += a7 * w.w;
        }
    }
#pragma unroll
    for (int i = 0; i < 8; ++i) {
        int gr = row0 + ty + 8 * i;
        if (gr < N_) {
            float s = scale ? scale[gr] : 1.0f;
            float4 v = acc[i];
            v.x *= s; v.y *= s; v.z *= s; v.w *= s;
            *(float4*)&out[(size_t)gr * 128 + (tx << 2)] = v;
        }
    }
}

// ---------------- GCN aggregate: h[i] = relu(di * sum_{s in nbr+self} m'[s])
// m' pre-scaled by dis[src] in GEMM epilogue. 32 lanes per node, float4
// row gathers, csr indices preloaded + shfl broadcast, unroll 8.
__global__ __launch_bounds__(256) void aggregate(
    const float* __restrict__ m, float* __restrict__ hout,
    const int* __restrict__ rowp, const int* __restrict__ csr,
    const float* __restrict__ dis, float* __restrict__ x2out) {
    int t = threadIdx.x;
    int lane = t & 63;
    int l32 = lane & 31;
    int hbase = lane & 32;                       // 0 | 32
    int node = blockIdx.x * 8 + ((t >> 6) << 1) + (hbase >> 5);   // N_ % 8 == 0
    const float4* m4 = (const float4*)m;

    float4 acc0 = m4[(size_t)node * 32 + l32];   // self-loop term
    float4 acc1 = make_float4(0.f, 0.f, 0.f, 0.f);
    int beg = rowp[node], end = rowp[node + 1];
    for (int base = beg; base < end; base += 32) {
        int cnt = end - base; if (cnt > 32) cnt = 32;
        int myidx = (l32 < cnt) ? csr[base + l32] : 0;
        int j = 0;
        for (; j + 8 <= cnt; j += 8) {
            int s0 = __shfl(myidx, hbase + j);
            int s1 = __shfl(myidx, hbase + j + 1);
            int s2 = __shfl(myidx, hbase + j + 2);
            int s3 = __shfl(myidx, hbase + j + 3);
            int s4 = __shfl(myidx, hbase + j + 4);
            int s5 = __shfl(myidx, hbase + j + 5);
            int s6 = __shfl(myidx, hbase + j + 6);
            int s7 = __shfl(myidx, hbase + j + 7);
            float4 v0 = m4[(size_t)s0 * 32 + l32];
            float4 v1 = m4[(size_t)s1 * 32 + l32];
            float4 v2 = m4[(size_t)s2 * 32 + l32];
            float4 v3 = m4[(size_t)s3 * 32 + l32];
            float4 v4 = m4[(size_t)s4 * 32 + l32];
            float4 v5 = m4[(size_t)s5 * 32 + l32];
            float4 v6 = m4[(size_t)s6 * 32 + l32];
            float4 v7 = m4[(size_t)s7 * 32 + l32];
            acc0.x += (v0.x + v1.x) + (v2.x + v3.x);
            acc0.y += (v0.y + v1.y) + (v2.y + v3.y);
            acc0.z += (v0.z + v1.z) + (v2.z + v3.z);
            acc0.w += (v0.w + v1.w) + (v2.w + v3.w);
            acc1.x += (v4.x + v5.x) + (v6.x + v7.x);
            acc1.y += (v4.y + v5.y) + (v6.y + v7.y);
            acc1.z += (v4.z + v5.z) + (v6.z + v7.z);
            acc1.w += (v4.w + v5.w) + (v6.w + v7.w);
        }
        for (; j + 4 <= cnt; j += 4) {
            int s0 = __shfl(myidx, hbase + j);
            int s1 = __shfl(myidx, hbase + j + 1);
            int s2 = __shfl(myidx, hbase + j + 2);
            int s3 = __shfl(myidx, hbase + j + 3);
            float4 v0 = m4[(size_t)s0 * 32 + l32];
            float4 v1 = m4[(size_t)s1 * 32 + l32];
            float4 v2 = m4[(size_t)s2 * 32 + l32];
            float4 v3 = m4[(size_t)s3 * 32 + l32];
            acc0.x += (v0.x + v1.x) + (v2.x + v3.x);
            acc0.y += (v0.y + v1.y) + (v2.y + v3.y);
            acc0.z += (v0.z + v1.z) + (v2.z + v3.z);
            acc0.w += (v0.w + v1.w) + (v2.w + v3.w);
        }
        for (; j < cnt; ++j) {
            int s = __shfl(myidx, hbase + j);
            float4 v = m4[(size_t)s * 32 + l32];
            acc1.x += v.x; acc1.y += v.y; acc1.z += v.z; acc1.w += v.w;
        }
    }
    float di = dis[node];
    float4 hv;
    hv.x = fmaxf(di * (acc0.x + acc1.x), 0.f);
    hv.y = fmaxf(di * (acc0.y + acc1.y), 0.f);
    hv.z = fmaxf(di * (acc0.z + acc1.z), 0.f);
    hv.w = fmaxf(di * (acc0.w + acc1.w), 0.f);
    ((float4*)hout)[(size_t)node * 32 + l32] = hv;
    if (x2out) {                                  // row norm, free in registers
        float p = hv.x * hv.x + hv.y * hv.y + hv.z * hv.z + hv.w * hv.w;
        p += __shfl_xor(p, 1);
        p += __shfl_xor(p, 2);
        p += __shfl_xor(p, 4);
        p += __shfl_xor(p, 8);
        p += __shfl_xor(p, 16);
        if (l32 == 0) x2out[node] = p;
    }
}

// ---------------- centroid norms ----------------
__global__ void c2_kernel(const float* __restrict__ cent, float* __restrict__ c2) {
    int c = blockIdx.x;
    int t = threadIdx.x;    // 64
    float v0 = cent[c * 128 + t];
    float v1 = cent[c * 128 + 64 + t];
    float p = v0 * v0 + v1 * v1;
    for (int off = 32; off > 0; off >>= 1) p += __shfl_down(p, off);
    if (t == 0) c2[c] = p;
}

// ---------------- per-graph mean-pool of distances (batch is sorted) -------
__global__ __launch_bounds__(128) void pool_graph(
    const float* __restrict__ dots, const float* __restrict__ x2,
    const float* __restrict__ c2, const int* __restrict__ batch,
    float* __restrict__ pooled) {
    int g = blockIdx.x;
    int t = threadIdx.x;
    int lo = 0, hi = N_;
    while (lo < hi) { int mid = (lo + hi) >> 1; if (batch[mid] < g) lo = mid + 1; else hi = mid; }
    int s = lo;
    hi = N_;
    while (lo < hi) { int mid = (lo + hi) >> 1; if (batch[mid] < g + 1) lo = mid + 1; else hi = mid; }
    int e = lo;
    if (t >= C_) return;
    float cv = c2[t];
    float a0 = 0.f, a1 = 0.f, a2 = 0.f, a3 = 0.f;
    int n = s;
    for (; n + 4 <= e; n += 4) {
        float d0 = dots[(size_t)(n    ) * 128 + t];
        float d1 = dots[(size_t)(n + 1) * 128 + t];
        float d2 = dots[(size_t)(n + 2) * 128 + t];
        float d3 = dots[(size_t)(n + 3) * 128 + t];
        float x0 = x2[n], x1 = x2[n + 1], x2v = x2[n + 2], x3 = x2[n + 3];
        a0 += sqrtf(fmaxf(x0  + cv - 2.f * d0, 0.f) + 1e-12f);
        a1 += sqrtf(fmaxf(x1  + cv - 2.f * d1, 0.f) + 1e-12f);
        a2 += sqrtf(fmaxf(x2v + cv - 2.f * d2, 0.f) + 1e-12f);
        a3 += sqrtf(fmaxf(x3  + cv - 2.f * d3, 0.f) + 1e-12f);
    }
    for (; n < e; ++n) {
        float d = dots[(size_t)n * 128 + t];
        a0 += sqrtf(fmaxf(x2[n] + cv - 2.f * d, 0.f) + 1e-12f);
    }
    float inv = 1.0f / fmaxf((float)(e - s), 1.0f);
    pooled[g * C_ + t] = (a0 + a1 + a2 + a3) * inv;
}

// ---------------- final: out = pooled @ W_out^T + b_out ----------------
__global__ void final_out(const float* __restrict__ pooled,
                          const float* __restrict__ W_out, const float* __restrict__ b_out,
                          float* __restrict__ out) {
    int i = blockIdx.x * 256 + threadIdx.x;
    if (i >= G_ * K_) return;
    int g = i >> 1, k = i & 1;
    float acc = 0.f;
    for (int c = 0; c < C_; ++c) acc += pooled[g * C_ + c] * W_out[k * C_ + c];
    out[i] = acc + b_out[k];
}

extern "C" void kernel_launch(void* const* d_in, const int* in_sizes, int n_in,
                              void* d_out, int out_size, void* d_ws, size_t ws_size,
                              hipStream_t stream) {
    const float* x       = (const float*)d_in[0];
    const int*   eidx    = (const int*)d_in[1];    // [2][E]: src then dst
    const int*   batch   = (const int*)d_in[2];
    const float* W_embed = (const float*)d_in[3];
    const float* W_convs = (const float*)d_in[4];
    const float* cent    = (const float*)d_in[5];
    const float* W_out   = (const float*)d_in[6];
    const float* b_out   = (const float*)d_in[7];
    float* out = (float*)d_out;

    char* p = (char*)d_ws;
    float* h    = (float*)p; p += (size_t)N_ * D_ * 4;
    float* m    = (float*)p; p += (size_t)N_ * D_ * 4;
    int*   deg  = (int*)p;   p += (size_t)N_ * 4;
    float* dis  = (float*)p; p += (size_t)N_ * 4;
    int*   rowp = (int*)p;   p += (size_t)(N_ + 2) * 4;
    int*   curs = (int*)p;   p += (size_t)N_ * 4;
    int*   csr  = (int*)p;   p += (size_t)E_ * 4;
    int*   bsum = (int*)p;   p += (size_t)512 * 4;
    float* c2   = (float*)p; p += (size_t)128 * 4;
    float* x2   = (float*)p; p += (size_t)N_ * 4;
    float* pool = (float*)p; p += (size_t)G_ * C_ * 4;

    const int* esrc = eidx;
    const int* edst = eidx + E_;

    init_ws<<<(N_ + 255) / 256, 256, 0, stream>>>(deg, curs);
    count_deg<<<(E_ + 255) / 256, 256, 0, stream>>>(edst, deg);
    compute_disq<<<(N_ + 255) / 256, 256, 0, stream>>>(deg, dis);
    scan_block_sums<<<NSB, 256, 0, stream>>>(deg, bsum);
    scan_offsets<<<1, 512, 0, stream>>>(bsum, NSB);
    scan_write<<<NSB, 256, 0, stream>>>(deg, bsum, rowp);
    fill_csr<<<(E_ + 255) / 256, 256, 0, stream>>>(esrc, edst, rowp, curs, csr);

    embed_kernel<<<(N_ + 63) / 64, 128, 0, stream>>>(x, W_embed, h);

    for (int l = 0; l < L_; ++l) {
        gcn_gemm<<<(N_ + 63) / 64, 256, 0, stream>>>(h, W_convs + (size_t)l * D_ * D_, m, 128, dis);
        aggregate<<<N_ / 8, 256, 0, stream>>>(m, h, rowp, csr, dis,
                                              (l == L_ - 1) ? x2 : nullptr);
    }

    // dots = h @ centroids^T  (cols 100..127 zero-padded)
    gcn_gemm<<<(N_ + 63) / 64, 256, 0, stream>>>(h, cent, m, 100, nullptr);
    c2_kernel<<<C_, 64, 0, stream>>>(cent, c2);
    pool_graph<<<G_, 128, 0, stream>>>(m, x2, c2, batch, pool);
    final_out<<<(G_ * K_ + 255) / 256, 256, 0, stream>>>(pool, W_out, b_out, out);
}